// Round 4
// baseline (2537.695 us; speedup 1.0000x reference)
//
#include <hip/hip_runtime.h>
#include <cstdint>

#define Tt 512
#define Bb 512
#define Ii 128
#define Hh 128
#define G4 512   // 4*H
#define S1 65    // stack slots
#define NSTEP 511

typedef float v2f __attribute__((ext_vector_type(2)));

__device__ __forceinline__ v2f fma2(v2f a, v2f b, v2f c) {
    return __builtin_elementwise_fma(a, b, c);
}
__device__ __forceinline__ float sigm(float x) {
    float e = __builtin_amdgcn_exp2f(x * -1.442695041f);
    return __builtin_amdgcn_rcpf(1.0f + e);
}
__device__ __forceinline__ float tanhx(float x) {
    float e = __builtin_amdgcn_exp2f(x * 2.885390082f);   // exp(2x)
    return 1.0f - 2.0f * __builtin_amdgcn_rcpf(e + 1.0f);
}

// add value from lane (l + N) within the 16-lane DPP row (row_shl:N);
// accumulates toward the LOW lane of each group. old=0 covers OOR lanes.
template <int CTRL>
__device__ __forceinline__ float dpp_add(float v) {
    int t = __builtin_amdgcn_update_dpp(0, __float_as_int(v), CTRL, 0xF, 0xF, true);
    return v + __int_as_float(t);
}
// sum over the 8 lanes of a ko-group; valid at lanes with (lane&7)==0
__device__ __forceinline__ float red8(float v) {
    v = dpp_add<0x104>(v);  // row_shl:4  (lane i += lane i+4)
    v = dpp_add<0x102>(v);  // row_shl:2
    v = dpp_add<0x101>(v);  // row_shl:1
    return v;
}

// ---------------- Input GEMM: scalar-broadcast matvec, no LDS ---------------
// One block (512 thr = 8 waves) per batch column b. Lane p owns the FULL
// 128-k dot for gate g=(p&3)*128+(p>>2); W_ih row pinned in 128 VGPRs.
// x row is wave-uniform -> scalar loads + v_fmac(VGPR, SGPR-broadcast).
// Store = 1 float/lane, consecutive p -> consecutive addresses; the (h,quad)
// interleave reproduces the float4-per-h gx layout rec_step reads.
__global__ __launch_bounds__(512, 2) void gx_gemm(
    const float* __restrict__ x,      // (steps, 512, 128), chunk base
    const float* __restrict__ W_ih,   // (512, 128)
    const float* __restrict__ b_ih,
    const float* __restrict__ b_hh,
    float* __restrict__ gx,           // float[(b*chcap + s)*512 + h*4 + quad]
    int chcap, int steps)
{
    const int p = threadIdx.x;
    const int b = blockIdx.x;
    const int g = (p & 3) * 128 + (p >> 2);

    float w[128];
    {
        const float4* wr = (const float4*)(W_ih + (size_t)g * Ii);
#pragma unroll
        for (int i = 0; i < 32; ++i) {
            float4 q = wr[i];
            w[4 * i] = q.x; w[4 * i + 1] = q.y; w[4 * i + 2] = q.z; w[4 * i + 3] = q.w;
        }
#pragma unroll
        for (int i = 0; i < 128; ++i) asm volatile("" : "+v"(w[i]));  // pin
    }
    const float bias = b_ih[g] + b_hh[g];

    for (int t = 0; t < steps; ++t) {
        const float4* xp = (const float4*)(x + ((size_t)t * Bb + b) * Ii);
        float a0 = 0.f, a1 = 0.f, a2 = 0.f, a3 = 0.f;
#pragma unroll
        for (int i = 0; i < 8; ++i) {
            float4 q = xp[i];
            a0 = fmaf(w[4 * i + 0], q.x, a0); a0 = fmaf(w[4 * i + 1], q.y, a0);
            a0 = fmaf(w[4 * i + 2], q.z, a0); a0 = fmaf(w[4 * i + 3], q.w, a0);
        }
#pragma unroll
        for (int i = 8; i < 16; ++i) {
            float4 q = xp[i];
            a1 = fmaf(w[4 * i + 0], q.x, a1); a1 = fmaf(w[4 * i + 1], q.y, a1);
            a1 = fmaf(w[4 * i + 2], q.z, a1); a1 = fmaf(w[4 * i + 3], q.w, a1);
        }
#pragma unroll
        for (int i = 16; i < 24; ++i) {
            float4 q = xp[i];
            a2 = fmaf(w[4 * i + 0], q.x, a2); a2 = fmaf(w[4 * i + 1], q.y, a2);
            a2 = fmaf(w[4 * i + 2], q.z, a2); a2 = fmaf(w[4 * i + 3], q.w, a2);
        }
#pragma unroll
        for (int i = 24; i < 32; ++i) {
            float4 q = xp[i];
            a3 = fmaf(w[4 * i + 0], q.x, a3); a3 = fmaf(w[4 * i + 1], q.y, a3);
            a3 = fmaf(w[4 * i + 2], q.z, a3); a3 = fmaf(w[4 * i + 3], q.w, a3);
        }
        gx[((size_t)b * chcap + t) * G4 + p] = a0 + a1 + a2 + a3 + bias;
    }
}

// ---------------- Recurrence: one block (1024 thr) per TWO batch elements ----
// 256 blocks -> exactly 1 per CU, all co-resident. (unchanged from round 3)
__global__ __launch_bounds__(1024, 4) void rec_step(
    const float* __restrict__ gxc,    // float4[(b*chcap + s)*128 + h]
    const int* __restrict__ ops,      // (T, B)
    const float* __restrict__ W_hh,   // (512, 128)
    const float* __restrict__ init_h,
    const float* __restrict__ init_c,
    float* __restrict__ out,          // (NSTEP, B, H)
    float* __restrict__ h_save,
    float* __restrict__ c_save,
    int* __restrict__ pt_save,
    int t0, int steps, int chcap, int first, int last)
{
    const int b0 = 2 * blockIdx.x;
    const int tid = threadIdx.x;
    const int h = tid >> 3;
    const int ko = tid & 7;

    __shared__ float h_st0[S1 * Hh];  // 33.25 KB each
    __shared__ float c_st0[S1 * Hh];
    __shared__ float h_st1[S1 * Hh];
    __shared__ float c_st1[S1 * Hh];
    __shared__ float4 g4[2][Hh];      // 4 KB reduced gates
    __shared__ int opsb[2][NSTEP + 1];// 4 KB

    v2f wv[4][8];
#pragma unroll
    for (int q = 0; q < 4; ++q) {
        const float4* wr = (const float4*)(W_hh + (size_t)(h + 128 * q) * Hh);
#pragma unroll
        for (int i = 0; i < 4; ++i) {
            float4 w4 = wr[i * 8 + ko];
            wv[q][2 * i]     = (v2f){w4.x, w4.y};
            wv[q][2 * i + 1] = (v2f){w4.z, w4.w};
        }
    }
#pragma unroll
    for (int q = 0; q < 4; ++q)
#pragma unroll
        for (int i = 0; i < 8; ++i) asm volatile("" : "+v"(wv[q][i]));  // pin

    if (first) {
        for (int i = tid; i < S1 * Hh; i += 1024) {
            const float hv = (i < Hh) ? init_h[i] : 0.f;
            const float cv = (i < Hh) ? init_c[i] : 0.f;
            h_st0[i] = hv; h_st1[i] = hv;
            c_st0[i] = cv; c_st1[i] = cv;
        }
    } else {
        const float* hs0 = h_save + (size_t)b0 * (S1 * Hh);
        const float* cs0 = c_save + (size_t)b0 * (S1 * Hh);
        const float* hs1 = hs0 + (S1 * Hh);
        const float* cs1 = cs0 + (S1 * Hh);
        for (int i = tid; i < S1 * Hh; i += 1024) {
            h_st0[i] = hs0[i]; c_st0[i] = cs0[i];
            h_st1[i] = hs1[i]; c_st1[i] = cs1[i];
        }
    }
    for (int i = tid; i <= steps; i += 1024) {
        const int2 o2 = *(const int2*)(ops + (size_t)(t0 + i) * Bb + b0);
        opsb[0][i] = o2.x;
        opsb[1][i] = o2.y;
    }
    int pt0 = 0, pt1 = 0;
    if (!first) { pt0 = pt_save[b0]; pt1 = pt_save[b0 + 1]; }

    const int bl = tid >> 7;          // 0 or 1 for cell threads (tid<256)
    const int hh = tid & 127;
    const float4* gq = (const float4*)gxc + ((size_t)(b0 + bl)) * chcap * Hh;
    float4 gxv = make_float4(0.f, 0.f, 0.f, 0.f);
    if (tid < 256) gxv = gq[hh];      // step 0
    __syncthreads();

    for (int s = 0; s < steps; ++s) {
        float4 gxn;
        if (tid < 256) {
            const int sn = (s + 1 < steps) ? (s + 1) : s;
            gxn = gq[(size_t)sn * Hh + hh];
        }

        pt0 += opsb[0][s];
        pt1 += opsb[1][s];

        // ---- matvec batch 0 ----
        {
            const float4* hq = (const float4*)(h_st0 + pt0 * Hh);
            v2f a0 = {0.f, 0.f}, a1 = a0, a2 = a0, a3 = a0;
#pragma unroll
            for (int i = 0; i < 4; ++i) {
                float4 hx = hq[i * 8 + ko];
                v2f lo = {hx.x, hx.y}, hi = {hx.z, hx.w};
                a0 = fma2(wv[0][2 * i], lo, a0); a0 = fma2(wv[0][2 * i + 1], hi, a0);
                a1 = fma2(wv[1][2 * i], lo, a1); a1 = fma2(wv[1][2 * i + 1], hi, a1);
                a2 = fma2(wv[2][2 * i], lo, a2); a2 = fma2(wv[2][2 * i + 1], hi, a2);
                a3 = fma2(wv[3][2 * i], lo, a3); a3 = fma2(wv[3][2 * i + 1], hi, a3);
            }
            float s0 = red8(a0.x + a0.y);
            float s1 = red8(a1.x + a1.y);
            float s2 = red8(a2.x + a2.y);
            float s3 = red8(a3.x + a3.y);
            if (ko == 0) g4[0][h] = make_float4(s0, s1, s2, s3);
        }
        // ---- matvec batch 1 ----
        {
            const float4* hq = (const float4*)(h_st1 + pt1 * Hh);
            v2f a0 = {0.f, 0.f}, a1 = a0, a2 = a0, a3 = a0;
#pragma unroll
            for (int i = 0; i < 4; ++i) {
                float4 hx = hq[i * 8 + ko];
                v2f lo = {hx.x, hx.y}, hi = {hx.z, hx.w};
                a0 = fma2(wv[0][2 * i], lo, a0); a0 = fma2(wv[0][2 * i + 1], hi, a0);
                a1 = fma2(wv[1][2 * i], lo, a1); a1 = fma2(wv[1][2 * i + 1], hi, a1);
                a2 = fma2(wv[2][2 * i], lo, a2); a2 = fma2(wv[2][2 * i + 1], hi, a2);
                a3 = fma2(wv[3][2 * i], lo, a3); a3 = fma2(wv[3][2 * i + 1], hi, a3);
            }
            float s0 = red8(a0.x + a0.y);
            float s1 = red8(a1.x + a1.y);
            float s2 = red8(a2.x + a2.y);
            float s3 = red8(a3.x + a3.y);
            if (ko == 0) g4[1][h] = make_float4(s0, s1, s2, s3);
        }
        __syncthreads();

        if (tid < 256) {              // 4 waves: (bl,hh) cell, one h each
            float* h_st = bl ? h_st1 : h_st0;
            float* c_st = bl ? c_st1 : c_st0;
            const int pt = bl ? pt1 : pt0;
            const float4 gg = g4[bl][hh];
            const float gi = gg.x + gxv.x;
            const float gf = gg.y + gxv.y;
            const float gG = gg.z + gxv.z;
            const float go = gg.w + gxv.w;
            const float cc = c_st[pt * Hh + hh];
            const float ch = h_st[pt * Hh + hh];
            const int pv = pt ? (pt - 1) : (S1 - 1);
            const float ph = h_st[pv * Hh + hh];
            const float nc = sigm(gf) * cc + sigm(gi) * tanhx(gG);
            const float nh = sigm(go) * tanhx(nc);
            c_st[(pt + 1) * Hh + hh] = nc;
            h_st[(pt + 1) * Hh + hh] = nh;
            const float opf = (float)opsb[bl][s + 1];
            const float af = fabsf(opf);
            const float ret = (nh * (1.f + opf) + ph * (1.f - opf)) * af + ch * (1.f - af);
            out[((size_t)(t0 + s) * Bb + (b0 + bl)) * Hh + hh] = ret;
            gxv = gxn;
        }
        __syncthreads();
    }

    if (!last) {
        float* hs0 = h_save + (size_t)b0 * (S1 * Hh);
        float* cs0 = c_save + (size_t)b0 * (S1 * Hh);
        float* hs1 = hs0 + (S1 * Hh);
        float* cs1 = cs0 + (S1 * Hh);
        for (int i = tid; i < S1 * Hh; i += 1024) {
            hs0[i] = h_st0[i]; cs0[i] = c_st0[i];
            hs1[i] = h_st1[i]; cs1[i] = c_st1[i];
        }
        if (tid == 0) { pt_save[b0] = pt0; pt_save[b0 + 1] = pt1; }
    }
}

extern "C" void kernel_launch(void* const* d_in, const int* in_sizes, int n_in,
                              void* d_out, int out_size, void* d_ws, size_t ws_size,
                              hipStream_t stream) {
    const float* inputs = (const float*)d_in[0];
    const int*   ops    = (const int*)d_in[1];
    const float* W_ih   = (const float*)d_in[2];
    const float* W_hh   = (const float*)d_in[3];
    const float* b_ih   = (const float*)d_in[4];
    const float* b_hh   = (const float*)d_in[5];
    const float* init_h = (const float*)d_in[6];
    const float* init_c = (const float*)d_in[7];
    float* out = (float*)d_out;

    // Adaptive chunking: if workspace fits the full (511,512,512) gx buffer
    // (~536 MB), do ONE chunk -> no h/c save/restore traffic at all.
    float* ws = (float*)d_ws;
    const size_t gx_full = (size_t)NSTEP * Bb * G4;              // floats
    const size_t save_f  = 2 * (size_t)Bb * S1 * Hh + 512;       // floats
    const size_t ws_f = ws_size / sizeof(float);

    int chcap;
    float *gxbuf, *h_sv, *c_sv;
    int* pt_sv;
    if (ws_f >= gx_full) {
        chcap = NSTEP;
        gxbuf = ws; h_sv = ws; c_sv = ws; pt_sv = (int*)ws;      // save bufs unused
    } else {
        h_sv  = ws;
        c_sv  = h_sv + (size_t)Bb * S1 * Hh;
        pt_sv = (int*)(c_sv + (size_t)Bb * S1 * Hh);
        gxbuf = (float*)(pt_sv + 512);                           // 16B-aligned
        const size_t avail = ws_f > save_f ? ws_f - save_f : 0;
        size_t cc = avail / ((size_t)Bb * G4);
        if (cc < 1) cc = 1;
        chcap = (cc > NSTEP) ? NSTEP : (int)cc;
    }

    int t0 = 0;
    while (t0 < NSTEP) {
        const int steps = (NSTEP - t0 < chcap) ? (NSTEP - t0) : chcap;
        gx_gemm<<<Bb, 512, 0, stream>>>(
            inputs + (size_t)t0 * Bb * Ii, W_ih, b_ih, b_hh, gxbuf, chcap, steps);
        rec_step<<<Bb / 2, 1024, 0, stream>>>(
            gxbuf, ops, W_hh, init_h, init_c, out,
            h_sv, c_sv, pt_sv, t0, steps, chcap,
            (t0 == 0) ? 1 : 0, (t0 + steps >= NSTEP) ? 1 : 0);
        t0 += steps;
    }
}

// Round 5
// 1453.779 us; speedup vs baseline: 1.7456x; 1.7456x over previous
//
#include <hip/hip_runtime.h>
#include <cstdint>

#define Tt 512
#define Bb 512
#define Ii 128
#define Hh 128
#define G4 512   // 4*H
#define S1 65    // stack slots
#define NSTEP 511
#define GROWS 128  // x rows staged per gx block

typedef float v2f __attribute__((ext_vector_type(2)));

__device__ __forceinline__ v2f fma2(v2f a, v2f b, v2f c) {
    return __builtin_elementwise_fma(a, b, c);
}
__device__ __forceinline__ float sigm(float x) {
    float e = __builtin_amdgcn_exp2f(x * -1.442695041f);
    return __builtin_amdgcn_rcpf(1.0f + e);
}
__device__ __forceinline__ float tanhx(float x) {
    float e = __builtin_amdgcn_exp2f(x * 2.885390082f);   // exp(2x)
    return 1.0f - 2.0f * __builtin_amdgcn_rcpf(e + 1.0f);
}

// add value from lane (l + N) within the 16-lane DPP row (row_shl:N);
// accumulates toward the LOW lane of each group. old=0 covers OOR lanes.
template <int CTRL>
__device__ __forceinline__ float dpp_add(float v) {
    int t = __builtin_amdgcn_update_dpp(0, __float_as_int(v), CTRL, 0xF, 0xF, true);
    return v + __int_as_float(t);
}
// sum over the 8 lanes of a ko-group; valid at lanes with (lane&7)==0
__device__ __forceinline__ float red8(float v) {
    v = dpp_add<0x104>(v);  // row_shl:4  (lane i += lane i+4)
    v = dpp_add<0x102>(v);  // row_shl:2
    v = dpp_add<0x101>(v);  // row_shl:1
    return v;
}

// Thread layout (both kernels): h = tid>>3 (0..127), ko = tid&7.
// Thread owns gate rows {h, h+128, h+256, h+384} restricted to k-quads
// {ko, 8+ko, 16+ko, 24+ko} (float4 units) -> 64 weight floats in VGPRs.

// ---------------- Input GEMM (round-3 version, measured ~587 us) ------------
__global__ __launch_bounds__(1024, 4) void gx_gemm(
    const float* __restrict__ x,      // (rows, 128), chunk base
    const float* __restrict__ W_ih,   // (512, 128)
    const float* __restrict__ b_ih,
    const float* __restrict__ b_hh,
    float* __restrict__ gx,           // float4[(b*chcap + s)*128 + h]
    int chcap)
{
    const int tid = threadIdx.x;
    const int h = tid >> 3;
    const int ko = tid & 7;

    v2f wv[4][8];
#pragma unroll
    for (int q = 0; q < 4; ++q) {
        const float4* wr = (const float4*)(W_ih + (size_t)(h + 128 * q) * Ii);
#pragma unroll
        for (int i = 0; i < 4; ++i) {
            float4 w4 = wr[i * 8 + ko];
            wv[q][2 * i]     = (v2f){w4.x, w4.y};
            wv[q][2 * i + 1] = (v2f){w4.z, w4.w};
        }
    }
#pragma unroll
    for (int q = 0; q < 4; ++q)
#pragma unroll
        for (int i = 0; i < 8; ++i) asm volatile("" : "+v"(wv[q][i]));

    float4 bias;
    bias.x = b_ih[h]       + b_hh[h];
    bias.y = b_ih[h + 128] + b_hh[h + 128];
    bias.z = b_ih[h + 256] + b_hh[h + 256];
    bias.w = b_ih[h + 384] + b_hh[h + 384];

    __shared__ float xs[GROWS * Ii];  // 64 KB
    const int m0 = blockIdx.x * GROWS;
    {
        const float4* src = (const float4*)(x + (size_t)m0 * Ii);
        float4* dst = (float4*)xs;
#pragma unroll
        for (int j = 0; j < 4; ++j) dst[tid + j * 1024] = src[tid + j * 1024];
    }
    __syncthreads();

    float4* gxq = (float4*)gx;
    for (int mi = 0; mi < GROWS; ++mi) {
        const float4* xr = (const float4*)(xs + mi * Ii);
        v2f a0 = {0.f, 0.f}, a1 = a0, a2 = a0, a3 = a0;
#pragma unroll
        for (int i = 0; i < 4; ++i) {
            float4 xx = xr[i * 8 + ko];
            v2f lo = {xx.x, xx.y}, hi = {xx.z, xx.w};
            a0 = fma2(wv[0][2 * i], lo, a0); a0 = fma2(wv[0][2 * i + 1], hi, a0);
            a1 = fma2(wv[1][2 * i], lo, a1); a1 = fma2(wv[1][2 * i + 1], hi, a1);
            a2 = fma2(wv[2][2 * i], lo, a2); a2 = fma2(wv[2][2 * i + 1], hi, a2);
            a3 = fma2(wv[3][2 * i], lo, a3); a3 = fma2(wv[3][2 * i + 1], hi, a3);
        }
        float s0 = red8(a0.x + a0.y);
        float s1 = red8(a1.x + a1.y);
        float s2 = red8(a2.x + a2.y);
        float s3 = red8(a3.x + a3.y);
        if (ko == 0) {
            const int m = m0 + mi;          // chunk-local row: m = s*512 + b
            const int s = m >> 9;
            const int bb = m & 511;
            gxq[((size_t)bb * chcap + s) * Hh + h] =
                make_float4(s0 + bias.x, s1 + bias.y, s2 + bias.z, s3 + bias.w);
        }
    }
}

// matvec for one batch: all 1024 threads; writes g4dst[h] at ko==0
#define MATVEC(hstate, ptv, g4dst)                                              \
    {                                                                           \
        const float4* hq = (const float4*)((hstate) + (ptv) * Hh);              \
        v2f a0 = {0.f, 0.f}, a1 = a0, a2 = a0, a3 = a0;                         \
        _Pragma("unroll") for (int i_ = 0; i_ < 4; ++i_) {                      \
            float4 hx = hq[i_ * 8 + ko];                                        \
            v2f lo = {hx.x, hx.y}, hi = {hx.z, hx.w};                           \
            a0 = fma2(wv[0][2 * i_], lo, a0); a0 = fma2(wv[0][2 * i_ + 1], hi, a0); \
            a1 = fma2(wv[1][2 * i_], lo, a1); a1 = fma2(wv[1][2 * i_ + 1], hi, a1); \
            a2 = fma2(wv[2][2 * i_], lo, a2); a2 = fma2(wv[2][2 * i_ + 1], hi, a2); \
            a3 = fma2(wv[3][2 * i_], lo, a3); a3 = fma2(wv[3][2 * i_ + 1], hi, a3); \
        }                                                                       \
        float s0 = red8(a0.x + a0.y);                                           \
        float s1 = red8(a1.x + a1.y);                                           \
        float s2 = red8(a2.x + a2.y);                                           \
        float s3 = red8(a3.x + a3.y);                                           \
        if (ko == 0) (g4dst)[h] = make_float4(s0, s1, s2, s3);                  \
    }

// cell update for (batch buffers, pt, step index st). Runs on 128 threads
// (hh = tid&127); consumes g4src[hh] + gxv, advances gxv <- gxn.
#define CELL(hstate, cstate, ptv, g4src, st, bidx)                              \
    {                                                                           \
        const float4 gg = (g4src)[hh];                                          \
        const float gi = gg.x + gxv.x;                                          \
        const float gf = gg.y + gxv.y;                                          \
        const float gG = gg.z + gxv.z;                                          \
        const float go = gg.w + gxv.w;                                          \
        const float cc = (cstate)[(ptv) * Hh + hh];                             \
        const float ch = (hstate)[(ptv) * Hh + hh];                             \
        const int pv = (ptv) ? ((ptv) - 1) : (S1 - 1);                          \
        const float ph = (hstate)[pv * Hh + hh];                                \
        const float nc = sigm(gf) * cc + sigm(gi) * tanhx(gG);                  \
        const float nh = sigm(go) * tanhx(nc);                                  \
        (cstate)[((ptv) + 1) * Hh + hh] = nc;                                   \
        (hstate)[((ptv) + 1) * Hh + hh] = nh;                                   \
        const float opf = (float)opsb[bidx][(st) + 1];                          \
        const float af = fabsf(opf);                                            \
        const float ret = (nh * (1.f + opf) + ph * (1.f - opf)) * af            \
                          + ch * (1.f - af);                                    \
        out[((size_t)(t0 + (st)) * Bb + (b0 + (bidx))) * Hh + hh] = ret;        \
        gxv = gxn;                                                              \
    }

// ---------------- Recurrence: 2 batches/block, SKEWED half-step pipeline ----
// P1: matvec b0(s) [all 16 waves] || cell b1(s-1) [waves 2-3]
// P2: matvec b1(s) [all 16 waves] || cell b0(s)   [waves 0-1]
// The former cell-only phase (12 idle waves) disappears; cell latency hides
// under the other batch's matvec.
__global__ __launch_bounds__(1024, 4) void rec_step(
    const float* __restrict__ gxc,    // float4[(b*chcap + s)*128 + h]
    const int* __restrict__ ops,      // (T, B)
    const float* __restrict__ W_hh,   // (512, 128)
    const float* __restrict__ init_h,
    const float* __restrict__ init_c,
    float* __restrict__ out,          // (NSTEP, B, H)
    float* __restrict__ h_save,
    float* __restrict__ c_save,
    int* __restrict__ pt_save,
    int t0, int steps, int chcap, int first, int last)
{
    const int b0 = 2 * blockIdx.x;
    const int tid = threadIdx.x;
    const int h = tid >> 3;
    const int ko = tid & 7;

    __shared__ float h_st0[S1 * Hh];  // 33.25 KB each
    __shared__ float c_st0[S1 * Hh];
    __shared__ float h_st1[S1 * Hh];
    __shared__ float c_st1[S1 * Hh];
    __shared__ float4 g4[2][Hh];      // 4 KB reduced gates
    __shared__ int opsb[2][NSTEP + 1];// 4 KB

    v2f wv[4][8];
#pragma unroll
    for (int q = 0; q < 4; ++q) {
        const float4* wr = (const float4*)(W_hh + (size_t)(h + 128 * q) * Hh);
#pragma unroll
        for (int i = 0; i < 4; ++i) {
            float4 w4 = wr[i * 8 + ko];
            wv[q][2 * i]     = (v2f){w4.x, w4.y};
            wv[q][2 * i + 1] = (v2f){w4.z, w4.w};
        }
    }
#pragma unroll
    for (int q = 0; q < 4; ++q)
#pragma unroll
        for (int i = 0; i < 8; ++i) asm volatile("" : "+v"(wv[q][i]));  // pin

    if (first) {
        for (int i = tid; i < S1 * Hh; i += 1024) {
            const float hv = (i < Hh) ? init_h[i] : 0.f;
            const float cv = (i < Hh) ? init_c[i] : 0.f;
            h_st0[i] = hv; h_st1[i] = hv;
            c_st0[i] = cv; c_st1[i] = cv;
        }
    } else {
        const float* hs0 = h_save + (size_t)b0 * (S1 * Hh);
        const float* cs0 = c_save + (size_t)b0 * (S1 * Hh);
        const float* hs1 = hs0 + (S1 * Hh);
        const float* cs1 = cs0 + (S1 * Hh);
        for (int i = tid; i < S1 * Hh; i += 1024) {
            h_st0[i] = hs0[i]; c_st0[i] = cs0[i];
            h_st1[i] = hs1[i]; c_st1[i] = cs1[i];
        }
    }
    for (int i = tid; i <= steps; i += 1024) {
        const int2 o2 = *(const int2*)(ops + (size_t)(t0 + i) * Bb + b0);
        opsb[0][i] = o2.x;
        opsb[1][i] = o2.y;
    }
    int pt0 = 0, pt1 = 0;
    if (!first) { pt0 = pt_save[b0]; pt1 = pt_save[b0 + 1]; }

    const int bl = tid >> 7;          // 0 or 1 for cell threads (tid<256)
    const int hh = tid & 127;
    const float4* gq = (const float4*)gxc + ((size_t)(b0 + bl)) * chcap * Hh;
    float4 gxv = make_float4(0.f, 0.f, 0.f, 0.f);
    if (tid < 256) gxv = gq[hh];      // gx[0] for both halves
    __syncthreads();

    for (int s = 0; s < steps; ++s) {
        // prefetch: b0-half needs gx[s+1] (consumed in P2 next... this iter's
        // P2 consumes gx[s]=gxv, then advances); b1-half needs gx[s]
        // (P1 of iter s+1 consumes gx[s]).
        float4 gxn;
        if (tid < 256) {
            const int sn = bl ? s : ((s + 1 < steps) ? s + 1 : s);
            gxn = gq[(size_t)sn * Hh + hh];
        }

        pt0 += opsb[0][s];

        // ---- P1: matvec b0(s) || cell b1(s-1) ----
        MATVEC(h_st0, pt0, g4[0])
        if (s > 0 && tid >= 128 && tid < 256) {
            CELL(h_st1, c_st1, pt1, g4[1], s - 1, 1)
        }
        __syncthreads();

        pt1 += opsb[1][s];

        // ---- P2: matvec b1(s) || cell b0(s) ----
        MATVEC(h_st1, pt1, g4[1])
        if (tid < 128) {
            CELL(h_st0, c_st0, pt0, g4[0], s, 0)
        }
        __syncthreads();
    }

    // epilogue: trailing cell b1(steps-1)
    if (tid >= 128 && tid < 256) {
        float4 gxn = gxv;  // unused advance target
        CELL(h_st1, c_st1, pt1, g4[1], steps - 1, 1)
    }
    __syncthreads();

    if (!last) {
        float* hs0 = h_save + (size_t)b0 * (S1 * Hh);
        float* cs0 = c_save + (size_t)b0 * (S1 * Hh);
        float* hs1 = hs0 + (S1 * Hh);
        float* cs1 = cs0 + (S1 * Hh);
        for (int i = tid; i < S1 * Hh; i += 1024) {
            hs0[i] = h_st0[i]; cs0[i] = c_st0[i];
            hs1[i] = h_st1[i]; cs1[i] = c_st1[i];
        }
        if (tid == 0) { pt_save[b0] = pt0; pt_save[b0 + 1] = pt1; }
    }
}

extern "C" void kernel_launch(void* const* d_in, const int* in_sizes, int n_in,
                              void* d_out, int out_size, void* d_ws, size_t ws_size,
                              hipStream_t stream) {
    const float* inputs = (const float*)d_in[0];
    const int*   ops    = (const int*)d_in[1];
    const float* W_ih   = (const float*)d_in[2];
    const float* W_hh   = (const float*)d_in[3];
    const float* b_ih   = (const float*)d_in[4];
    const float* b_hh   = (const float*)d_in[5];
    const float* init_h = (const float*)d_in[6];
    const float* init_c = (const float*)d_in[7];
    float* out = (float*)d_out;

    // Adaptive chunking: if workspace fits the full (511,512,512) gx buffer
    // (~536 MB), do ONE chunk -> no h/c save/restore traffic at all.
    float* ws = (float*)d_ws;
    const size_t gx_full = (size_t)NSTEP * Bb * G4;              // floats
    const size_t save_f  = 2 * (size_t)Bb * S1 * Hh + 512;       // floats
    const size_t ws_f = ws_size / sizeof(float);

    int chcap;
    float *gxbuf, *h_sv, *c_sv;
    int* pt_sv;
    if (ws_f >= gx_full) {
        chcap = NSTEP;
        gxbuf = ws; h_sv = ws; c_sv = ws; pt_sv = (int*)ws;      // save bufs unused
    } else {
        h_sv  = ws;
        c_sv  = h_sv + (size_t)Bb * S1 * Hh;
        pt_sv = (int*)(c_sv + (size_t)Bb * S1 * Hh);
        gxbuf = (float*)(pt_sv + 512);                           // 16B-aligned
        const size_t avail = ws_f > save_f ? ws_f - save_f : 0;
        size_t cc = avail / ((size_t)Bb * G4);
        if (cc < 1) cc = 1;
        chcap = (cc > NSTEP) ? NSTEP : (int)cc;
    }

    int t0 = 0;
    while (t0 < NSTEP) {
        const int steps = (NSTEP - t0 < chcap) ? (NSTEP - t0) : chcap;
        gx_gemm<<<steps * Bb / GROWS, 1024, 0, stream>>>(
            inputs + (size_t)t0 * Bb * Ii, W_ih, b_ih, b_hh, gxbuf, chcap);
        rec_step<<<Bb / 2, 1024, 0, stream>>>(
            gxbuf, ops, W_hh, init_h, init_c, out,
            h_sv, c_sv, pt_sv, t0, steps, chcap,
            (t0 == 0) ? 1 : 0, (t0 + steps >= NSTEP) ? 1 : 0);
        t0 += steps;
    }
}

// Round 7
// 1025.815 us; speedup vs baseline: 2.4738x; 1.4172x over previous
//
#include <hip/hip_runtime.h>
#include <cstdint>

#define Tt 512
#define Bb 512
#define Ii 128
#define Hh 128
#define G4 512   // 4*H
#define S1 65    // stack slots
#define NSTEP 511

typedef float v2f __attribute__((ext_vector_type(2)));
typedef short s16x8 __attribute__((ext_vector_type(8)));
typedef short s16x4 __attribute__((ext_vector_type(4)));
typedef float f32x4 __attribute__((ext_vector_type(4)));

__device__ __forceinline__ v2f fma2(v2f a, v2f b, v2f c) {
    return __builtin_elementwise_fma(a, b, c);
}
__device__ __forceinline__ float sigm(float x) {
    float e = __builtin_amdgcn_exp2f(x * -1.442695041f);
    return __builtin_amdgcn_rcpf(1.0f + e);
}
__device__ __forceinline__ float tanhx(float x) {
    float e = __builtin_amdgcn_exp2f(x * 2.885390082f);   // exp(2x)
    return 1.0f - 2.0f * __builtin_amdgcn_rcpf(e + 1.0f);
}

// add value from lane (l + N) within the 16-lane DPP row (row_shl:N);
// accumulates toward the LOW lane of each group. old=0 covers OOR lanes.
template <int CTRL>
__device__ __forceinline__ float dpp_add(float v) {
    int t = __builtin_amdgcn_update_dpp(0, __float_as_int(v), CTRL, 0xF, 0xF, true);
    return v + __int_as_float(t);
}
__device__ __forceinline__ float red8(float v) {
    v = dpp_add<0x104>(v);  // row_shl:4
    v = dpp_add<0x102>(v);  // row_shl:2
    v = dpp_add<0x101>(v);  // row_shl:1
    return v;
}

// bf16 round-to-nearest-even helpers
__device__ __forceinline__ unsigned short bfr(float x) {
    unsigned int u = __float_as_uint(x);
    return (unsigned short)((u + 0x7FFFu + ((u >> 16) & 1u)) >> 16);
}
__device__ __forceinline__ float bff(unsigned short h) {
    return __uint_as_float(((unsigned int)h) << 16);
}

// ---------------- Input GEMM via MFMA, 3-term bf16 split --------------------
// Block = 512 thr (8 waves), handles 2 timesteps (1024 rows), iterating
// N-tiles of 16 batch-rows. Wave w owns M-tiles T = 4w..4w+3 with PERMUTED
// A rows: tile-row m -> gate g = 128*(m&3) + 4T + (m>>2), so each lane's 4
// acc regs = gates {h, h+128, h+256, h+384} = one gx float4 at h = 4T+lg.
// gates = (Whi+Wlo)·(xhi+xlo) ~= Whi·xhi + Whi·xlo + Wlo·xhi (err ~2^-18).
__global__ __launch_bounds__(512, 2) void gx_mfma(
    const float* __restrict__ x,      // (steps, 512, 128), chunk base
    const float* __restrict__ W_ih,   // (512, 128)
    const float* __restrict__ b_ih,
    const float* __restrict__ b_hh,
    float* __restrict__ gx,           // float4[(b*chcap + s)*128 + h]
    int chcap, int steps)
{
    const int tid = threadIdx.x;
    const int wid = tid >> 6;
    const int l = tid & 63;
    const int lm = l & 15;      // m (A-row slot) / n (B-col) within tile
    const int lg = l >> 4;      // k-octet group

    __shared__ short xhi[16 * 136];   // 16 rows x 128 bf16, row pad to 136
    __shared__ short xlo[16 * 136];
    __shared__ float trb[16 * 516];   // transpose buffer, row pad to 516
    __shared__ float4 biasq[128];

    if (tid < 128)
        biasq[tid] = make_float4(b_ih[tid] + b_hh[tid],
                                 b_ih[tid + 128] + b_hh[tid + 128],
                                 b_ih[tid + 256] + b_hh[tid + 256],
                                 b_ih[tid + 384] + b_hh[tid + 384]);

    // A fragments (persistent): hi/lo bf16, 4 tiles x 4 k-steps
    s16x8 ahi[4][4], alo[4][4];
#pragma unroll
    for (int t = 0; t < 4; ++t) {
        const int T = wid * 4 + t;
        const int g = 128 * (lm & 3) + 4 * T + (lm >> 2);   // permuted row
        const float* wr = W_ih + (size_t)g * Ii;
#pragma unroll
        for (int ks = 0; ks < 4; ++ks) {
            const float4 w0 = *(const float4*)(wr + 32 * ks + 8 * lg);
            const float4 w1 = *(const float4*)(wr + 32 * ks + 8 * lg + 4);
            const float wf[8] = {w0.x, w0.y, w0.z, w0.w, w1.x, w1.y, w1.z, w1.w};
            s16x8 h8, l8;
#pragma unroll
            for (int i = 0; i < 8; ++i) {
                const unsigned short hb = bfr(wf[i]);
                h8[i] = (short)hb;
                l8[i] = (short)bfr(wf[i] - bff(hb));
            }
            ahi[t][ks] = h8;
            alo[t][ks] = l8;
        }
    }

    const int s0 = 2 * blockIdx.x;
    const int nS = (steps - s0 >= 2) ? 2 : 1;
    const int QT = nS * 32;           // N-iters: 32 per timestep

    const int xr = tid >> 5;          // stage row 0..15
    const int xk = tid & 31;          // float4 index within row

    float4 xv, xn;
    xv = *(const float4*)(x + ((size_t)s0 * Bb + xr) * Ii + 4 * xk);

    for (int q = 0; q < QT; ++q) {
        const int s = s0 + (q >> 5);
        const int n0 = (q & 31) * 16;

        // ---- stage x tile as bf16 hi/lo ----
        {
            const float xf[4] = {xv.x, xv.y, xv.z, xv.w};
            s16x4 h4, l4;
#pragma unroll
            for (int i = 0; i < 4; ++i) {
                const unsigned short hb = bfr(xf[i]);
                h4[i] = (short)hb;
                l4[i] = (short)bfr(xf[i] - bff(hb));
            }
            *(s16x4*)(xhi + xr * 136 + 4 * xk) = h4;
            *(s16x4*)(xlo + xr * 136 + 4 * xk) = l4;
        }
        __syncthreads();

        // ---- prefetch next x tile (hidden under MFMA) ----
        {
            const int qn = (q + 1 < QT) ? q + 1 : q;
            const int sn = s0 + (qn >> 5);
            const int nn = (qn & 31) * 16;
            xn = *(const float4*)(x + ((size_t)sn * Bb + nn + xr) * Ii + 4 * xk);
        }

        // ---- MFMA: 4 tiles x 4 ksteps x 3 terms ----
        f32x4 acc[4] = {{0.f,0.f,0.f,0.f},{0.f,0.f,0.f,0.f},
                        {0.f,0.f,0.f,0.f},{0.f,0.f,0.f,0.f}};
#pragma unroll
        for (int ks = 0; ks < 4; ++ks) {
            const s16x8 bhi = *(const s16x8*)(xhi + lm * 136 + 32 * ks + 8 * lg);
            const s16x8 blo = *(const s16x8*)(xlo + lm * 136 + 32 * ks + 8 * lg);
#pragma unroll
            for (int t = 0; t < 4; ++t) {
                acc[t] = __builtin_amdgcn_mfma_f32_16x16x32_bf16(ahi[t][ks], bhi, acc[t], 0, 0, 0);
                acc[t] = __builtin_amdgcn_mfma_f32_16x16x32_bf16(ahi[t][ks], blo, acc[t], 0, 0, 0);
                acc[t] = __builtin_amdgcn_mfma_f32_16x16x32_bf16(alo[t][ks], bhi, acc[t], 0, 0, 0);
            }
        }

        // ---- transpose-store: lane holds gx float4 of h = 4T+lg, batch lm ----
#pragma unroll
        for (int t = 0; t < 4; ++t) {
            const int T = wid * 4 + t;
            *(f32x4*)(trb + lm * 516 + (4 * T + lg) * 4) = acc[t];
        }
        __syncthreads();

        // ---- readback + bias + coalesced store ----
        {
            float4* gxq = (float4*)gx;
            const int r2 = tid >> 5;
#pragma unroll
            for (int j = 0; j < 4; ++j) {
                const int i = (tid & 31) + 32 * j;
                const f32x4 v = *(const f32x4*)(trb + r2 * 516 + 4 * i);
                const float4 bq = biasq[i];
                gxq[((size_t)(n0 + r2) * chcap + s) * Hh + i] =
                    make_float4(v[0] + bq.x, v[1] + bq.y, v[2] + bq.z, v[3] + bq.w);
            }
        }
        __syncthreads();
        xv = xn;
    }
}

// ---------------- Recurrence: EXACT round-3 kernel (best measured: ~810us) --
__global__ __launch_bounds__(1024, 4) void rec_step(
    const float* __restrict__ gxc,    // float4[(b*chcap + s)*128 + h]
    const int* __restrict__ ops,      // (T, B)
    const float* __restrict__ W_hh,   // (512, 128)
    const float* __restrict__ init_h,
    const float* __restrict__ init_c,
    float* __restrict__ out,          // (NSTEP, B, H)
    float* __restrict__ h_save,
    float* __restrict__ c_save,
    int* __restrict__ pt_save,
    int t0, int steps, int chcap, int first, int last)
{
    const int b0 = 2 * blockIdx.x;
    const int tid = threadIdx.x;
    const int h = tid >> 3;
    const int ko = tid & 7;

    __shared__ float h_st0[S1 * Hh];
    __shared__ float c_st0[S1 * Hh];
    __shared__ float h_st1[S1 * Hh];
    __shared__ float c_st1[S1 * Hh];
    __shared__ float4 g4[2][Hh];
    __shared__ int opsb[2][NSTEP + 1];

    v2f wv[4][8];
#pragma unroll
    for (int q = 0; q < 4; ++q) {
        const float4* wr = (const float4*)(W_hh + (size_t)(h + 128 * q) * Hh);
#pragma unroll
        for (int i = 0; i < 4; ++i) {
            float4 w4 = wr[i * 8 + ko];
            wv[q][2 * i]     = (v2f){w4.x, w4.y};
            wv[q][2 * i + 1] = (v2f){w4.z, w4.w};
        }
    }
#pragma unroll
    for (int q = 0; q < 4; ++q)
#pragma unroll
        for (int i = 0; i < 8; ++i) asm volatile("" : "+v"(wv[q][i]));  // pin

    if (first) {
        for (int i = tid; i < S1 * Hh; i += 1024) {
            const float hv = (i < Hh) ? init_h[i] : 0.f;
            const float cv = (i < Hh) ? init_c[i] : 0.f;
            h_st0[i] = hv; h_st1[i] = hv;
            c_st0[i] = cv; c_st1[i] = cv;
        }
    } else {
        const float* hs0 = h_save + (size_t)b0 * (S1 * Hh);
        const float* cs0 = c_save + (size_t)b0 * (S1 * Hh);
        const float* hs1 = hs0 + (S1 * Hh);
        const float* cs1 = cs0 + (S1 * Hh);
        for (int i = tid; i < S1 * Hh; i += 1024) {
            h_st0[i] = hs0[i]; c_st0[i] = cs0[i];
            h_st1[i] = hs1[i]; c_st1[i] = cs1[i];
        }
    }
    for (int i = tid; i <= steps; i += 1024) {
        const int2 o2 = *(const int2*)(ops + (size_t)(t0 + i) * Bb + b0);
        opsb[0][i] = o2.x;
        opsb[1][i] = o2.y;
    }
    int pt0 = 0, pt1 = 0;
    if (!first) { pt0 = pt_save[b0]; pt1 = pt_save[b0 + 1]; }

    const int bl = tid >> 7;
    const int hh = tid & 127;
    const float4* gq = (const float4*)gxc + ((size_t)(b0 + bl)) * chcap * Hh;
    float4 gxv = make_float4(0.f, 0.f, 0.f, 0.f);
    if (tid < 256) gxv = gq[hh];
    __syncthreads();

    for (int s = 0; s < steps; ++s) {
        float4 gxn;
        if (tid < 256) {
            const int sn = (s + 1 < steps) ? (s + 1) : s;
            gxn = gq[(size_t)sn * Hh + hh];
        }

        pt0 += opsb[0][s];
        pt1 += opsb[1][s];

        // ---- matvec batch 0 ----
        {
            const float4* hq = (const float4*)(h_st0 + pt0 * Hh);
            v2f a0 = {0.f, 0.f}, a1 = a0, a2 = a0, a3 = a0;
#pragma unroll
            for (int i = 0; i < 4; ++i) {
                float4 hx = hq[i * 8 + ko];
                v2f lo = {hx.x, hx.y}, hi = {hx.z, hx.w};
                a0 = fma2(wv[0][2 * i], lo, a0); a0 = fma2(wv[0][2 * i + 1], hi, a0);
                a1 = fma2(wv[1][2 * i], lo, a1); a1 = fma2(wv[1][2 * i + 1], hi, a1);
                a2 = fma2(wv[2][2 * i], lo, a2); a2 = fma2(wv[2][2 * i + 1], hi, a2);
                a3 = fma2(wv[3][2 * i], lo, a3); a3 = fma2(wv[3][2 * i + 1], hi, a3);
            }
            float s0 = red8(a0.x + a0.y);
            float s1 = red8(a1.x + a1.y);
            float s2 = red8(a2.x + a2.y);
            float s3 = red8(a3.x + a3.y);
            if (ko == 0) g4[0][h] = make_float4(s0, s1, s2, s3);
        }
        // ---- matvec batch 1 ----
        {
            const float4* hq = (const float4*)(h_st1 + pt1 * Hh);
            v2f a0 = {0.f, 0.f}, a1 = a0, a2 = a0, a3 = a0;
#pragma unroll
            for (int i = 0; i < 4; ++i) {
                float4 hx = hq[i * 8 + ko];
                v2f lo = {hx.x, hx.y}, hi = {hx.z, hx.w};
                a0 = fma2(wv[0][2 * i], lo, a0); a0 = fma2(wv[0][2 * i + 1], hi, a0);
                a1 = fma2(wv[1][2 * i], lo, a1); a1 = fma2(wv[1][2 * i + 1], hi, a1);
                a2 = fma2(wv[2][2 * i], lo, a2); a2 = fma2(wv[2][2 * i + 1], hi, a2);
                a3 = fma2(wv[3][2 * i], lo, a3); a3 = fma2(wv[3][2 * i + 1], hi, a3);
            }
            float s0 = red8(a0.x + a0.y);
            float s1 = red8(a1.x + a1.y);
            float s2 = red8(a2.x + a2.y);
            float s3 = red8(a3.x + a3.y);
            if (ko == 0) g4[1][h] = make_float4(s0, s1, s2, s3);
        }
        __syncthreads();

        if (tid < 256) {
            float* h_st = bl ? h_st1 : h_st0;
            float* c_st = bl ? c_st1 : c_st0;
            const int pt = bl ? pt1 : pt0;
            const float4 gg = g4[bl][hh];
            const float gi = gg.x + gxv.x;
            const float gf = gg.y + gxv.y;
            const float gG = gg.z + gxv.z;
            const float go = gg.w + gxv.w;
            const float cc = c_st[pt * Hh + hh];
            const float ch = h_st[pt * Hh + hh];
            const int pv = pt ? (pt - 1) : (S1 - 1);
            const float ph = h_st[pv * Hh + hh];
            const float nc = sigm(gf) * cc + sigm(gi) * tanhx(gG);
            const float nh = sigm(go) * tanhx(nc);
            c_st[(pt + 1) * Hh + hh] = nc;
            h_st[(pt + 1) * Hh + hh] = nh;
            const float opf = (float)opsb[bl][s + 1];
            const float af = fabsf(opf);
            const float ret = (nh * (1.f + opf) + ph * (1.f - opf)) * af + ch * (1.f - af);
            out[((size_t)(t0 + s) * Bb + (b0 + bl)) * Hh + hh] = ret;
            gxv = gxn;
        }
        __syncthreads();
    }

    if (!last) {
        float* hs0 = h_save + (size_t)b0 * (S1 * Hh);
        float* cs0 = c_save + (size_t)b0 * (S1 * Hh);
        float* hs1 = hs0 + (S1 * Hh);
        float* cs1 = cs0 + (S1 * Hh);
        for (int i = tid; i < S1 * Hh; i += 1024) {
            hs0[i] = h_st0[i]; cs0[i] = c_st0[i];
            hs1[i] = h_st1[i]; cs1[i] = c_st1[i];
        }
        if (tid == 0) { pt_save[b0] = pt0; pt_save[b0 + 1] = pt1; }
    }
}

extern "C" void kernel_launch(void* const* d_in, const int* in_sizes, int n_in,
                              void* d_out, int out_size, void* d_ws, size_t ws_size,
                              hipStream_t stream) {
    const float* inputs = (const float*)d_in[0];
    const int*   ops    = (const int*)d_in[1];
    const float* W_ih   = (const float*)d_in[2];
    const float* W_hh   = (const float*)d_in[3];
    const float* b_ih   = (const float*)d_in[4];
    const float* b_hh   = (const float*)d_in[5];
    const float* init_h = (const float*)d_in[6];
    const float* init_c = (const float*)d_in[7];
    float* out = (float*)d_out;

    // Adaptive chunking: if workspace fits the full (511,512,512) gx buffer
    // (~536 MB), do ONE chunk -> no h/c save/restore traffic at all.
    float* ws = (float*)d_ws;
    const size_t gx_full = (size_t)NSTEP * Bb * G4;              // floats
    const size_t save_f  = 2 * (size_t)Bb * S1 * Hh + 512;       // floats
    const size_t ws_f = ws_size / sizeof(float);

    int chcap;
    float *gxbuf, *h_sv, *c_sv;
    int* pt_sv;
    if (ws_f >= gx_full) {
        chcap = NSTEP;
        gxbuf = ws; h_sv = ws; c_sv = ws; pt_sv = (int*)ws;      // save bufs unused
    } else {
        h_sv  = ws;
        c_sv  = h_sv + (size_t)Bb * S1 * Hh;
        pt_sv = (int*)(c_sv + (size_t)Bb * S1 * Hh);
        gxbuf = (float*)(pt_sv + 512);                           // 16B-aligned
        const size_t avail = ws_f > save_f ? ws_f - save_f : 0;
        size_t cc = avail / ((size_t)Bb * G4);
        if (cc < 1) cc = 1;
        chcap = (cc > NSTEP) ? NSTEP : (int)cc;
    }

    int t0 = 0;
    while (t0 < NSTEP) {
        const int steps = (NSTEP - t0 < chcap) ? (NSTEP - t0) : chcap;
        gx_mfma<<<(steps + 1) / 2, 512, 0, stream>>>(
            inputs + (size_t)t0 * Bb * Ii, W_ih, b_ih, b_hh, gxbuf, chcap, steps);
        rec_step<<<Bb / 2, 1024, 0, stream>>>(
            gxbuf, ops, W_hh, init_h, init_c, out,
            h_sv, c_sv, pt_sv, t0, steps, chcap,
            (t0 == 0) ? 1 : 0, (t0 + steps >= NSTEP) ? 1 : 0);
        t0 += steps;
    }
}